// Round 3
// baseline (42.835 us; speedup 1.0000x reference)
//
#include <hip/hip_runtime.h>

// Problem constants (match reference)
#define BB 16
#define CC 8
#define HW (512 * 512)          // pixels per image
#define IGNORE_IDX 255
#define EPS_F 1e-5f
#define MINPIX 10.0f

// Launch config
#define BPI 64                  // blocks per image
#define NTHR 256
#define NBLK (BB * BPI)         // 1024 stage-1 blocks
#define PPB (HW / BPI)          // 4096 pixels per block

// ws layout (floats):
//   [0      .. 8192)   inter[b][c][chunk]   (16*8*64)
//   [8192   .. 16384)  psum [b][c][chunk]
//   [16384  .. 24576)  tsum [b][c][chunk]
//   [24576  .. 25600)  ce_partial[block]
//   [25600  .. 26624)  cnt_partial[block]
#define OFF_INTER 0
#define OFF_PSUM  8192
#define OFF_TSUM  16384
#define OFF_CE    24576
#define OFF_CNT   (24576 + NBLK)

__device__ __forceinline__ float wave_red(float v) {
#pragma unroll
    for (int o = 32; o > 0; o >>= 1) v += __shfl_xor(v, o, 64);
    return v;
}

__global__ __launch_bounds__(NTHR) void focal_stage1(
    const float* __restrict__ logits, const int* __restrict__ tgt,
    float* __restrict__ ws)
{
    const int b     = blockIdx.x / BPI;
    const int chunk = blockIdx.x % BPI;
    const float* base = logits + (size_t)b * (CC * HW);
    const int*   tb   = tgt    + (size_t)b * HW;
    const int start = chunk * PPB;

    float psum[8]  = {0.f,0.f,0.f,0.f,0.f,0.f,0.f,0.f};
    float inter[8] = {0.f,0.f,0.f,0.f,0.f,0.f,0.f,0.f};
    int   tcnt[8]  = {0,0,0,0,0,0,0,0};
    float ce = 0.f;
    int   cnt = 0;

    for (int it = 0; it < PPB; it += NTHR * 4) {
        const int pix = start + it + (int)threadIdx.x * 4;
        const int4 t4 = *reinterpret_cast<const int4*>(tb + pix);
        float4 v[8];
#pragma unroll
        for (int c = 0; c < 8; ++c)
            v[c] = *reinterpret_cast<const float4*>(base + (size_t)c * HW + pix);

#pragma unroll
        for (int j = 0; j < 4; ++j) {
            const int t = (&t4.x)[j];
            float x[8];
#pragma unroll
            for (int c = 0; c < 8; ++c) x[c] = (&v[c].x)[j];

            float m = x[0];
#pragma unroll
            for (int c = 1; c < 8; ++c) m = fmaxf(m, x[c]);

            float e[8];
            float s = 0.f;
#pragma unroll
            for (int c = 0; c < 8; ++c) { e[c] = __expf(x[c] - m); s += e[c]; }
            const float inv = 1.0f / s;

            const bool valid = (t != IGNORE_IDX);
            float xt = 0.f, et = 0.f;
#pragma unroll
            for (int c = 0; c < 8; ++c) {
                const float pc = e[c] * inv;
                psum[c] += valid ? pc : 0.f;
                const bool hit = valid && (t == c);
                inter[c] += hit ? pc : 0.f;
                tcnt[c]  += hit ? 1 : 0;
                xt = (t == c) ? x[c] : xt;   // compile-time-unrolled select, no scratch
                et = (t == c) ? e[c] : et;
            }
            const float pt    = et * inv;
            const float logpt = (xt - m) - __logf(s);
            const float omp   = 1.f - pt;
            ce  += valid ? -(omp * omp) * logpt : 0.f;
            cnt += valid ? 1 : 0;
        }
    }

    // ---- block reduction: wave shuffle -> LDS -> single write per value ----
    __shared__ float sm[4][26];
    const int wave = threadIdx.x >> 6;
    const int lane = threadIdx.x & 63;

    float red[26];
#pragma unroll
    for (int c = 0; c < 8; ++c) red[c]      = inter[c];
#pragma unroll
    for (int c = 0; c < 8; ++c) red[8 + c]  = psum[c];
#pragma unroll
    for (int c = 0; c < 8; ++c) red[16 + c] = (float)tcnt[c];
    red[24] = ce;
    red[25] = (float)cnt;

#pragma unroll
    for (int k = 0; k < 26; ++k) {
        const float r = wave_red(red[k]);
        if (lane == 0) sm[wave][k] = r;
    }
    __syncthreads();

    const int tid = threadIdx.x;
    if (tid < 26) {
        const float tot = sm[0][tid] + sm[1][tid] + sm[2][tid] + sm[3][tid];
        if (tid < 8)
            ws[OFF_INTER + ((b * CC + tid) * BPI) + chunk] = tot;
        else if (tid < 16)
            ws[OFF_PSUM + ((b * CC + (tid - 8)) * BPI) + chunk] = tot;
        else if (tid < 24)
            ws[OFF_TSUM + ((b * CC + (tid - 16)) * BPI) + chunk] = tot;
        else if (tid == 24)
            ws[OFF_CE + blockIdx.x] = tot;
        else
            ws[OFF_CNT + blockIdx.x] = tot;
    }
}

__global__ __launch_bounds__(NTHR) void focal_stage2(
    const float* __restrict__ ws, float* __restrict__ out)
{
    const int tid = threadIdx.x;

    // per-(b,c) dice term
    float dval = 0.f;
    if (tid < BB * CC) {
        const int c = tid & 7;
        const int off = tid * BPI;   // (b*CC + c) * BPI
        float I = 0.f, P = 0.f, T = 0.f;
        for (int k = 0; k < BPI; ++k) {
            I += ws[OFF_INTER + off + k];
            P += ws[OFF_PSUM  + off + k];
            T += ws[OFF_TSUM  + off + k];
        }
        if (c >= 1 && T > MINPIX)
            dval = 1.f - (2.f * I + EPS_F) / (P + T + EPS_F);
    }

    // ce partials
    float ce = 0.f, cn = 0.f;
    for (int k = tid; k < NBLK; k += NTHR) {
        ce += ws[OFF_CE + k];
        cn += ws[OFF_CNT + k];
    }

    dval = wave_red(dval);
    ce   = wave_red(ce);
    cn   = wave_red(cn);

    __shared__ float sd[3][4];
    const int wave = tid >> 6;
    const int lane = tid & 63;
    if (lane == 0) { sd[0][wave] = dval; sd[1][wave] = ce; sd[2][wave] = cn; }
    __syncthreads();

    if (tid == 0) {
        const float D  = sd[0][0] + sd[0][1] + sd[0][2] + sd[0][3];
        const float CE = sd[1][0] + sd[1][1] + sd[1][2] + sd[1][3];
        const float CN = sd[2][0] + sd[2][1] + sd[2][2] + sd[2][3];
        out[0] = (CE / CN) + 0.1f * (D / ((CC - 1) * (float)BB));
    }
}

extern "C" void kernel_launch(void* const* d_in, const int* in_sizes, int n_in,
                              void* d_out, int out_size, void* d_ws, size_t ws_size,
                              hipStream_t stream)
{
    const float* logits = (const float*)d_in[0];
    const int*   tgt    = (const int*)d_in[1];
    float*       ws     = (float*)d_ws;
    float*       out    = (float*)d_out;

    focal_stage1<<<NBLK, NTHR, 0, stream>>>(logits, tgt, ws);
    focal_stage2<<<1, NTHR, 0, stream>>>(ws, out);
}